// Round 4
// baseline (3073.709 us; speedup 1.0000x reference)
//
#include <hip/hip_runtime.h>

// LSTM: H=1024, B=1024, S=128 (T=127 steps), E=6, V=3, C=10.
// R16: persistent + LDS-resident weights (R14/R15) with PULL-MODEL exchange:
// no L2 invalidates at all.
//  - Coherence dual: plain reads only touch data written through the LOCAL
//    L2 by LOCAL blocks. Per step each XCD stages the 512 KB of h its
//    32 blocks need into a per-XCD, parity-2 staging buffer xcdbuf:
//      A (epilogue): block sc0sc1-stores its 8 KB h-chunk to global hbuf
//        (cross-XCD medium) AND plain-stores it into the local xcdbuf;
//        posts pflag[q] (sc) + lcnt[xcc] += 1 (device atomic).
//      B (fetch): block polls ONE flag (its partner = same rank, other XCD
//        of the pair), sc-reads the partner's 8 KB from L3, plain-stores it
//        into local xcdbuf, lcnt[xcc] += 1.
//      C (gate, next step): poll lcnt[xcc] >= 64*t (all 32 blocks x 2
//        events), vL1-only buffer_inv, then the K-loop reads h from xcdbuf
//        with plain loads -> all warm-L2 hits (~200 cyc).
//  - No leader, no release chain, no buffer_inv sc1, no 32-way L3 refetch
//    storm: removes R15's tail-latency amplification (34.7 ms outlier).
//  - Parity-2 hbuf/xcdbuf proven sufficient: gate(t+2) on XCD 2p implies all
//    of the pair's B(t) completed (via partner-flag chain), so no overwrite
//    of a buffer still being read.
//  - c state in registers all 127 steps; t=0 reads h0 straight from global
//    (L2 clean at kernel start), so xcdbuf needs no seeding.
constexpr int kH = 1024;
constexpr int kB = 1024;
constexpr int kS = 128;
constexpr int kT = 127;
constexpr int kE = 6;
constexpr int kV = 3;
constexpr int kC = 10;

typedef short s16x8 __attribute__((ext_vector_type(8)));
typedef short s16x4 __attribute__((ext_vector_type(4)));
typedef float f32x4 __attribute__((ext_vector_type(4)));
typedef int   i32x2 __attribute__((ext_vector_type(2)));
typedef int   i32x4 __attribute__((ext_vector_type(4)));
typedef unsigned short u16;

__device__ __forceinline__ float b2f(u16 u) {
    return __uint_as_float(((unsigned)u) << 16);
}
__device__ __forceinline__ u16 f2b(float f) {
    unsigned u = __float_as_uint(f);
    return (u16)((u + 0x7FFFu + ((u >> 16) & 1u)) >> 16);   // RNE
}
__device__ __forceinline__ float sigmoid_fast(float x) {
    return 1.0f / (1.0f + __expf(-x));
}
__device__ __forceinline__ float tanh_fast(float x) {
    return 2.0f / (1.0f + __expf(-2.0f * x)) - 1.0f;
}
__device__ __forceinline__ float clamp30(float x) {
    return fminf(fmaxf(x, -30.0f), 30.0f);
}

__device__ __forceinline__ void async_copy16(const u16* g, u16* l) {
    __builtin_amdgcn_global_load_lds(
        (const __attribute__((address_space(1))) void*)g,
        (__attribute__((address_space(3))) void*)l, 16, 0, 0);
}

// ---------------------------------------------------------------------------
// Prep 1: weights fp32 -> bf16, frag-major (identical to R8..R15):
//   grp = (((by*4 + kc)*4 + g)*8 + k0)*64 + lane
//   wsw[grp*8 + j] = W_g[by*16 + (lane&15)][kc*256 + k0*32 + (lane>>4)*8 + j]
// ---------------------------------------------------------------------------
__global__ __launch_bounds__(256) void prep_weights(
    const float* __restrict__ Wgh, const float* __restrict__ Wih,
    const float* __restrict__ Wfh, const float* __restrict__ Woh,
    u16* __restrict__ wsw)
{
    unsigned grp = blockIdx.x * 256 + threadIdx.x;    // 0 .. 2^19-1
    const int lane = grp & 63;
    const int lm   = lane & 15;
    const int quad = lane >> 4;
    const int k0   = (grp >> 6) & 7;
    const int g    = (grp >> 9) & 3;
    const int kc   = (grp >> 11) & 3;
    const int by   = grp >> 13;                       // 0..63
    const float* src = (g == 0) ? Wgh : (g == 1) ? Wih : (g == 2) ? Wfh : Woh;
    const int row = by * 16 + lm;
    const int k   = kc * 256 + k0 * 32 + quad * 8;
    f32x4 v0 = *(const f32x4*)(src + (size_t)row * kH + k);
    f32x4 v1 = *(const f32x4*)(src + (size_t)row * kH + k + 4);
    s16x8 o;
#pragma unroll
    for (int j = 0; j < 4; ++j) o[j] = (short)f2b(v0[j]);
#pragma unroll
    for (int j = 0; j < 4; ++j) o[4 + j] = (short)f2b(v1[j]);
    *(s16x8*)(wsw + (size_t)grp * 8) = o;
}

// ---------------------------------------------------------------------------
// Prep 2: transpose h0 (H,B) fp32 -> hA (B,H) bf16; c0 (H,B) -> cT (B,H) fp32.
// ---------------------------------------------------------------------------
__global__ __launch_bounds__(1024) void prep_hc(
    const float* __restrict__ h0, const float* __restrict__ c0,
    u16* __restrict__ hA, float* __restrict__ cT)
{
    __shared__ float th[32][33];
    __shared__ float tc[32][33];
    int b = blockIdx.x * 32 + threadIdx.x;
    int h = blockIdx.y * 32 + threadIdx.y;
    th[threadIdx.y][threadIdx.x] = h0[(size_t)h * kB + b];
    tc[threadIdx.y][threadIdx.x] = c0[(size_t)h * kB + b];
    __syncthreads();
    int ob = blockIdx.x * 32 + threadIdx.y;
    int oh = blockIdx.y * 32 + threadIdx.x;
    hA[(size_t)ob * kH + oh] = f2b(th[threadIdx.x][threadIdx.y]);
    cT[(size_t)ob * kH + oh] = tc[threadIdx.x][threadIdx.y];
}

// ---------------------------------------------------------------------------
// Prep 3: gate constants repacked as f32x4 (unchanged), plus zeroing the
// control block: pflag[256] @0, lcnt[8] @256, rankCnt[8] @264 -- all within
// ctrl[0..511], re-zeroed every graph replay, stream-ordered before the
// persistent kernel.
// ---------------------------------------------------------------------------
__global__ __launch_bounds__(256) void prep_q(
    const float* __restrict__ Wgx, const float* __restrict__ Wix,
    const float* __restrict__ Wfx, const float* __restrict__ Wox,
    const float* __restrict__ bg,  const float* __restrict__ bi,
    const float* __restrict__ bf_, const float* __restrict__ bo,
    const float* __restrict__ emb, float* __restrict__ Qp,
    int* __restrict__ ctrl)
{
    int tid = blockIdx.x * blockDim.x + threadIdx.x;   // 0..4095
    if (tid < 512) ctrl[tid] = 0;
    if (tid >= 4096) return;
    int g   = tid >> 10;
    int hr4 = (tid & 1023) >> 2;
    int v   = tid & 3;
    const float* Wx = (g == 0) ? Wgx : (g == 1) ? Wix : (g == 2) ? Wfx : Wox;
    const float* bb = (g == 0) ? bg  : (g == 1) ? bi  : (g == 2) ? bf_ : bo;
    f32x4 o;
#pragma unroll
    for (int reg = 0; reg < 4; ++reg) {
        int row = hr4 * 4 + reg;
        float s = bb[row];
        if (v < kV) {
#pragma unroll
            for (int e = 0; e < kE; ++e) s += Wx[row * kE + e] * emb[v * kE + e];
        }
        o[reg] = s;
    }
    *(f32x4*)(Qp + (size_t)tid * 4) = o;
}

// ---------------------------------------------------------------------------
// Persistent LSTM: 256 blocks x 512 thr (1 block/CU, 8 waves), weights
// LDS-resident, pull-model h exchange (no L2 invalidates).
// Identity: xcc = XCC_ID, rank = arrival order in XCD (0..31).
// p = xcc>>1 (col-group, 256 cols), side = xcc&1, q = side*32+rank (row-
// group), partner = (1-side)*32+rank on the pair's other XCD.
// ---------------------------------------------------------------------------
__global__ __launch_bounds__(512, 2) void lstm_persist(
    const u16* __restrict__ wsw, const float* __restrict__ Qp,
    const int* __restrict__ x,
    short* __restrict__ hA, short* __restrict__ hB,
    const float* __restrict__ cT, int* __restrict__ ctrl,
    u16* __restrict__ xcb)
{
    __shared__ u16 wlds[65536];   // 128 KB, resident all 127 steps
    __shared__ int sh_ids[2];

    const int tid  = threadIdx.x;
    const int lane = tid & 63;
    const int wave = tid >> 6;              // 0..7
    const int lm   = lane & 15;
    const int quad = lane >> 4;

    // ---- runtime identity: XCD id + arrival rank within XCD ----
    if (tid == 0) {
        unsigned xccr;
        asm volatile("s_getreg_b32 %0, hwreg(HW_REG_XCC_ID)" : "=s"(xccr));
        int rank = atomicAdd(ctrl + 264 + (xccr & 7), 1);
        sh_ids[0] = (int)(xccr & 7);
        sh_ids[1] = rank;
    }
    __syncthreads();
    const int xcc   = sh_ids[0];
    const int rank  = sh_ids[1];              // 0..31 within XCD
    const int p     = xcc >> 1;               // col-group 0..3 (XCD pair)
    const int side  = xcc & 1;
    const int q     = side * 32 + rank;       // row-group 0..63 within pair
    const int qprt  = (1 - side) * 32 + rank; // partner row-group
    const int r0 = q * 16;
    const int cl0 = wave * 32;                // wave's local col base (0..255)
    const int c0 = p * 256 + cl0;             // global col base

    int* pflag = ctrl;              // [p*64 + q], monotonic step counters
    int* lcnt  = ctrl + 256;        // [xcc], monotonic arrival counters

    const u16* wswblk = wsw + (size_t)q * 65536;

    // ---- stage the whole weight slice once (async, 128 KB) ----
#pragma unroll
    for (int rr = 0; rr < 16; ++rr) {
        const int ub = wave * 8192 + rr * 512;   // shorts
        async_copy16(wswblk + ub + lane * 8, &wlds[ub]);
    }

    // ---- persistent c state: loaded once, lives in registers 127 steps ----
    f32x4 creg[2];
#pragma unroll
    for (int nt = 0; nt < 2; ++nt)
        creg[nt] = *(const f32x4*)(cT +
            (size_t)(c0 + nt * 16 + lm) * kH + r0 + quad * 4);

    const int* xp0 = x + (size_t)(c0 + lm) * kS;
    const int* xp1 = x + (size_t)(c0 + 16 + lm) * kS;
    const int koff = quad * 8;

    asm volatile("s_waitcnt vmcnt(0)" ::: "memory");
    __syncthreads();   // weights resident from here on

#pragma unroll 1
    for (int t = 0; t < kT; ++t) {
        short* hout = (t & 1) ? hA : hB;   // h_{t+1} global (cross-XCD medium)
        // xcdbuf parity: h_v lives at parity v&1. Step t reads h_t, writes h_{t+1}.
        u16* xw = xcb + (size_t)(xcc * 2 + ((t + 1) & 1)) * 262144;

        // ---- C gate: wait for all 64 staging events of step t-1 ----
        if (t >= 1) {
            if (tid == 0) {
                const int* cp = lcnt + xcc;
                const int tgt = 64 * t;
                for (;;) {
                    int v;
                    asm volatile("global_load_dword %0, %1, off sc0 sc1\n\t"
                                 "s_waitcnt vmcnt(0)"
                                 : "=v"(v) : "v"(cp) : "memory");
                    if (v >= tgt) break;
                    __builtin_amdgcn_s_sleep(1);
                }
            }
            __syncthreads();
            // vL1-only invalidate: xcdbuf lines from step t-2 may be cached.
            asm volatile("buffer_inv" ::: "memory");
        }

        // ---- h source: t=0 straight from global h0 (L2 clean at kernel
        //      start); t>=1 from the local XCD staging buffer (warm L2). ----
        const u16* xr = xcb + (size_t)(xcc * 2 + (t & 1)) * 262144;
        const u16* hrow0;
        const u16* hrow1;
        if (t == 0) {
            hrow0 = (const u16*)hA + (size_t)(c0 + lm) * kH + koff;
            hrow1 = (const u16*)hA + (size_t)(c0 + 16 + lm) * kH + koff;
        } else {
            hrow0 = xr + (size_t)(cl0 + lm) * kH + koff;
            hrow1 = xr + (size_t)(cl0 + 16 + lm) * kH + koff;
        }

        // ---- b-ring prologue: slots 0..5 (8-slot ring, lookahead 6) ----
        s16x8 br[8][2];
#pragma unroll
        for (int s = 0; s < 6; ++s) {
            br[s][0] = *(const s16x8*)(hrow0 + s * 32);
            br[s][1] = *(const s16x8*)(hrow1 + s * 32);
        }

        // ---- per-step loads: x -> vv -> Qp vectors ----
        int vv[2];
        {
            int v0 = xp0[t]; vv[0] = (v0 < 0) ? 0 : (v0 > kV - 1) ? (kV - 1) : v0;
            int v1 = xp1[t]; vv[1] = (v1 < 0) ? 0 : (v1 > kV - 1) ? (kV - 1) : v1;
        }
        f32x4 qv[2][4];
#pragma unroll
        for (int nt = 0; nt < 2; ++nt)
#pragma unroll
            for (int g = 0; g < 4; ++g)
                qv[nt][g] = *(const f32x4*)(Qp +
                    (size_t)(((g * 256 + q * 4 + quad) * 4 + vv[nt]) * 4));

        f32x4 acc[4][2];
        const f32x4 zero = {0.f, 0.f, 0.f, 0.f};
#pragma unroll
        for (int g = 0; g < 4; ++g)
#pragma unroll
            for (int n = 0; n < 2; ++n) acc[g][n] = zero;

        // ---- main K loop: 32 x (4 ds_read_b128 + 8 MFMA), ring loads ----
#pragma unroll
        for (int k0 = 0; k0 < 32; ++k0) {
            if (k0 + 6 < 32) {
                const int s = (k0 + 6) & 7;
                br[s][0] = *(const s16x8*)(hrow0 + (k0 + 6) * 32);
                br[s][1] = *(const s16x8*)(hrow1 + (k0 + 6) * 32);
            }
            const int cur = k0 & 7;
            const int cb = (k0 >> 3) * 16384;         // K-chunk base (shorts)
#pragma unroll
            for (int g = 0; g < 4; ++g) {
                const int f = cb + ((g * 8 + (k0 & 7)) * 64 + lane) * 8;
                s16x8 a = *(const s16x8*)&wlds[f];
                acc[g][0] = __builtin_amdgcn_mfma_f32_16x16x32_bf16(a, br[cur][0], acc[g][0], 0, 0, 0);
                acc[g][1] = __builtin_amdgcn_mfma_f32_16x16x32_bf16(a, br[cur][1], acc[g][1], 0, 0, 0);
            }
        }

        // ---- A: epilogue ALU + dual store (sc -> hbuf, plain -> xcdbuf) ----
#pragma unroll
        for (int nt = 0; nt < 2; ++nt) {
            const int cl = cl0 + nt * 16 + lm;         // local col 0..255
            const int c  = p * 256 + cl;               // global col
            const int rb = r0 + quad * 4;
            f32x4 cnew;
            s16x4 hnew;
#pragma unroll
            for (int reg = 0; reg < 4; ++reg) {
                float pg = clamp30(acc[0][nt][reg] + qv[nt][0][reg]);
                float pi = clamp30(acc[1][nt][reg] + qv[nt][1][reg]);
                float pf = clamp30(acc[2][nt][reg] + qv[nt][2][reg]);
                float po = clamp30(acc[3][nt][reg] + qv[nt][3][reg]);
                float gg = tanh_fast(pg);
                float ii = sigmoid_fast(pi);
                float ff = sigmoid_fast(pf);
                float oo = sigmoid_fast(po);
                float c2 = gg * ii + creg[nt][reg] * ff;
                c2 = fminf(fmaxf(c2, -200.0f), 200.0f);
                cnew[reg] = c2;
                hnew[reg] = (short)f2b(tanh_fast(c2) * oo);
            }
            creg[nt] = cnew;
            i32x2 hv;
            __builtin_memcpy(&hv, &hnew, 8);
            short* hp = hout + (size_t)c * kH + rb;
            // write-through to L3: cross-XCD medium (partner fetch + logits)
            asm volatile("global_store_dwordx2 %0, %1, off sc0 sc1"
                         :: "v"(hp), "v"(hv) : "memory");
            // local copy through this XCD's L2 (consumed by local K-loops)
            *(s16x4*)(xw + (size_t)cl * kH + rb) = hnew;
        }

        if (t < kT - 1) {
            asm volatile("s_waitcnt vmcnt(0)" ::: "memory");  // both stores done
            __syncthreads();                                  // block done
            if (tid == 0) {
                // own chunk staged: signal partner (sc) + local count (atomic)
                int* fp = pflag + p * 64 + q;
                int fv = t + 1;
                asm volatile("global_store_dword %0, %1, off sc0 sc1\n\t"
                             "s_waitcnt vmcnt(0)"
                             :: "v"(fp), "v"(fv) : "memory");
                atomicAdd(lcnt + xcc, 1);
                // ---- B: wait for partner's chunk in L3 ----
                const int* pp = pflag + p * 64 + qprt;
                for (;;) {
                    int v;
                    asm volatile("global_load_dword %0, %1, off sc0 sc1\n\t"
                                 "s_waitcnt vmcnt(0)"
                                 : "=v"(v) : "v"(pp) : "memory");
                    if (v >= t + 1) break;
                    __builtin_amdgcn_s_sleep(1);
                }
            }
            __syncthreads();
            // fetch partner's 8 KB chunk: 512 thr x 16 B (sc read, plain store)
            {
                const int cl   = tid >> 1;
                const int half = tid & 1;
                const short* src = hout + (size_t)(p * 256 + cl) * kH +
                                   qprt * 16 + half * 8;
                u16* dst = xw + (size_t)cl * kH + qprt * 16 + half * 8;
                i32x4 v;
                asm volatile("global_load_dwordx4 %0, %1, off sc0 sc1\n\t"
                             "s_waitcnt vmcnt(0)"
                             : "=v"(v) : "v"(src) : "memory");
                *(i32x4*)dst = v;
            }
            asm volatile("s_waitcnt vmcnt(0)" ::: "memory");  // plain store done
            __syncthreads();
            if (tid == 0) atomicAdd(lcnt + xcc, 1);           // partner staged
        }
    }
}

// ---------------------------------------------------------------------------
// Logits: p[b][cls] = h[b,:] . W_ph[cls,:] + b_p[cls]; log_softmax over 10.
// ---------------------------------------------------------------------------
__global__ __launch_bounds__(256) void logits_kernel(
    const u16* __restrict__ hT, const float* __restrict__ Wph,
    const float* __restrict__ bp, float* __restrict__ out)
{
    const int wave = threadIdx.x >> 6;
    const int lane = threadIdx.x & 63;
    const int b = blockIdx.x * 4 + wave;

    const u16* hp = hT + (size_t)b * kH + lane * 16;
    float hf[16];
#pragma unroll
    for (int j = 0; j < 16; ++j) hf[j] = b2f(hp[j]);

    float p[kC];
#pragma unroll
    for (int cls = 0; cls < kC; ++cls) {
        const float* wp = Wph + (size_t)cls * kH + lane * 16;
        float s = 0.f;
#pragma unroll
        for (int j = 0; j < 16; ++j) s += hf[j] * wp[j];
#pragma unroll
        for (int off = 1; off < 64; off <<= 1) s += __shfl_xor(s, off, 64);
        p[cls] = fminf(fmaxf(s + bp[cls], -1.0e4f), 1.0e4f);
    }

    float m = p[0];
#pragma unroll
    for (int cls = 1; cls < kC; ++cls) m = fmaxf(m, p[cls]);
    float se = 0.f;
#pragma unroll
    for (int cls = 0; cls < kC; ++cls) se += __expf(p[cls] - m);
    float l = m + __logf(se);

    if (lane < kC) {
        float myp = p[0];
#pragma unroll
        for (int cls = 1; cls < kC; ++cls)
            if (lane == cls) myp = p[cls];
        out[(size_t)b * kC + lane] = myp - l;
    }
}

// ---------------------------------------------------------------------------
extern "C" void kernel_launch(void* const* d_in, const int* in_sizes, int n_in,
                              void* d_out, int out_size, void* d_ws, size_t ws_size,
                              hipStream_t stream)
{
    const int*   x   = (const int*)  d_in[0];
    const float* emb = (const float*)d_in[1];
    const float* Wgx = (const float*)d_in[2];
    const float* Wgh = (const float*)d_in[3];
    const float* bg  = (const float*)d_in[4];
    const float* Wix = (const float*)d_in[5];
    const float* Wih = (const float*)d_in[6];
    const float* bi  = (const float*)d_in[7];
    const float* Wfx = (const float*)d_in[8];
    const float* Wfh = (const float*)d_in[9];
    const float* bf_ = (const float*)d_in[10];
    const float* Wox = (const float*)d_in[11];
    const float* Woh = (const float*)d_in[12];
    const float* bo  = (const float*)d_in[13];
    const float* Wph = (const float*)d_in[14];
    const float* bp  = (const float*)d_in[15];
    const float* h0  = (const float*)d_in[16];
    const float* c0  = (const float*)d_in[17];

    char* ws = (char*)d_ws;
    float* Qp  = (float*)ws;                              // 64 KB
    u16*   hA  = (u16*)(ws + (64 << 10));                 // 2 MB
    u16*   hB  = hA + (size_t)kB * kH;                    // 2 MB
    float* cT  = (float*)(hB + (size_t)kB * kH);          // 4 MB
    u16*   wsw = (u16*)(cT + (size_t)kB * kH);            // 8 MB
    u16*   xcb = wsw + (size_t)64 * 65536;                // 8 MB (16 x 512 KB)
    int*   ctrl = (int*)(xcb + (size_t)16 * 262144);      // 2 KB (total ~24.1 MB)

    prep_weights<<<dim3(2048), dim3(256), 0, stream>>>(Wgh, Wih, Wfh, Woh, wsw);
    prep_hc<<<dim3(kB / 32, kH / 32), dim3(32, 32), 0, stream>>>(h0, c0, hA, cT);
    prep_q<<<dim3(16), dim3(256), 0, stream>>>(Wgx, Wix, Wfx, Wox, bg, bi, bf_, bo,
                                               emb, Qp, ctrl);

    lstm_persist<<<dim3(256), dim3(512), 0, stream>>>(
        wsw, Qp, x, (short*)hA, (short*)hB, cT, ctrl, xcb);

    // 127 steps: t=126 (even) wrote hB.
    logits_kernel<<<dim3(kB / 4), dim3(256), 0, stream>>>(hB, Wph, bp, (float*)d_out);
}

// Round 6
// 3006.461 us; speedup vs baseline: 1.0224x; 1.0224x over previous
//
#include <hip/hip_runtime.h>

// LSTM: H=1024, B=1024, S=128 (T=127 steps), E=6, V=3, C=10.
// R18 = R17 with the hang fixed. R17 post-mortem: the lcnt/rcnt counter
// polls used sc0-only loads. Device atomics are performed at the coherent
// point PAST the local L2, so an sc0 poll can hit a stale clean L2 line
// forever -> infinite spin -> container killed. R16 (passed) polled the
// same counters with sc0 sc1. R18 restores sc0 sc1 on ALL control-word
// polls; everything else is identical to R17:
//  - persistent 256 blocks x 512 thr (1 block/CU), weights LDS-resident,
//    K-SPLIT overlap exchange: LOCAL K-half (rows produced on this XCD,
//    exchanged via plain stores through the local L2) first; mid-step
//    coalesced 8 KB partner fetch (flag long-set by then); REMOTE K-half
//    on the freshly staged data. No L2 invalidates anywhere, only vL1.
//  - hbuf [rowgrp 64][col 1024][16] so partner chunks are contiguous 8 KB;
//    xcdbuf per (xcc,parity) [col 256][k 1024]; prep seeds parity-0 xcdbuf.
//  - c state in registers all 127 steps; epilogue numerics identical.
constexpr int kH = 1024;
constexpr int kB = 1024;
constexpr int kS = 128;
constexpr int kT = 127;
constexpr int kE = 6;
constexpr int kV = 3;
constexpr int kC = 10;

typedef short s16x8 __attribute__((ext_vector_type(8)));
typedef short s16x4 __attribute__((ext_vector_type(4)));
typedef float f32x4 __attribute__((ext_vector_type(4)));
typedef int   i32x2 __attribute__((ext_vector_type(2)));
typedef int   i32x4 __attribute__((ext_vector_type(4)));
typedef unsigned short u16;

__device__ __forceinline__ float b2f(u16 u) {
    return __uint_as_float(((unsigned)u) << 16);
}
__device__ __forceinline__ u16 f2b(float f) {
    unsigned u = __float_as_uint(f);
    return (u16)((u + 0x7FFFu + ((u >> 16) & 1u)) >> 16);   // RNE
}
__device__ __forceinline__ float sigmoid_fast(float x) {
    return 1.0f / (1.0f + __expf(-x));
}
__device__ __forceinline__ float tanh_fast(float x) {
    return 2.0f / (1.0f + __expf(-2.0f * x)) - 1.0f;
}
__device__ __forceinline__ float clamp30(float x) {
    return fminf(fmaxf(x, -30.0f), 30.0f);
}

__device__ __forceinline__ void async_copy16(const u16* g, u16* l) {
    __builtin_amdgcn_global_load_lds(
        (const __attribute__((address_space(1))) void*)g,
        (__attribute__((address_space(3))) void*)l, 16, 0, 0);
}

// ---------------------------------------------------------------------------
// Prep 1: weights fp32 -> bf16, frag-major (identical to R8..R17):
//   grp = (((by*4 + kc)*4 + g)*8 + k0)*64 + lane
//   wsw[grp*8 + j] = W_g[by*16 + (lane&15)][kc*256 + k0*32 + (lane>>4)*8 + j]
// ---------------------------------------------------------------------------
__global__ __launch_bounds__(256) void prep_weights(
    const float* __restrict__ Wgh, const float* __restrict__ Wih,
    const float* __restrict__ Wfh, const float* __restrict__ Woh,
    u16* __restrict__ wsw)
{
    unsigned grp = blockIdx.x * 256 + threadIdx.x;    // 0 .. 2^19-1
    const int lane = grp & 63;
    const int lm   = lane & 15;
    const int quad = lane >> 4;
    const int k0   = (grp >> 6) & 7;
    const int g    = (grp >> 9) & 3;
    const int kc   = (grp >> 11) & 3;
    const int by   = grp >> 13;                       // 0..63
    const float* src = (g == 0) ? Wgh : (g == 1) ? Wih : (g == 2) ? Wfh : Woh;
    const int row = by * 16 + lm;
    const int k   = kc * 256 + k0 * 32 + quad * 8;
    f32x4 v0 = *(const f32x4*)(src + (size_t)row * kH + k);
    f32x4 v1 = *(const f32x4*)(src + (size_t)row * kH + k + 4);
    s16x8 o;
#pragma unroll
    for (int j = 0; j < 4; ++j) o[j] = (short)f2b(v0[j]);
#pragma unroll
    for (int j = 0; j < 4; ++j) o[4 + j] = (short)f2b(v1[j]);
    *(s16x8*)(wsw + (size_t)grp * 8) = o;
}

// ---------------------------------------------------------------------------
// Prep 2: transpose h0 (H,B) -> seed each XCD's parity-0 xcdbuf ([col][k]
// bf16, both XCDs of the pair owning that col-group); c0 (H,B) -> cT (B,H).
// ---------------------------------------------------------------------------
__global__ __launch_bounds__(1024) void prep_hc(
    const float* __restrict__ h0, const float* __restrict__ c0,
    u16* __restrict__ xcb, float* __restrict__ cT)
{
    __shared__ float th[32][33];
    __shared__ float tc[32][33];
    int b = blockIdx.x * 32 + threadIdx.x;
    int h = blockIdx.y * 32 + threadIdx.y;
    th[threadIdx.y][threadIdx.x] = h0[(size_t)h * kB + b];
    tc[threadIdx.y][threadIdx.x] = c0[(size_t)h * kB + b];
    __syncthreads();
    int ob = blockIdx.x * 32 + threadIdx.y;   // batch/col
    int oh = blockIdx.y * 32 + threadIdx.x;   // h row (k)
    cT[(size_t)ob * kH + oh] = tc[threadIdx.x][threadIdx.y];
    u16 hv = f2b(th[threadIdx.x][threadIdx.y]);
    int pg = ob >> 8;                          // col-group 0..3
    size_t off = (size_t)(ob & 255) * kH + oh;
    xcb[((size_t)(2 * pg) * 2 + 0) * 262144 + off] = hv;      // xcc = 2p
    xcb[((size_t)(2 * pg + 1) * 2 + 0) * 262144 + off] = hv;  // xcc = 2p+1
}

// ---------------------------------------------------------------------------
// Prep 3: gate constants repacked as f32x4 (unchanged), plus zeroing the
// control block: pflag[256]@0, lcnt[8]@256, rcnt[8]@272, rankCnt[8]@288 --
// all within ctrl[0..511], re-zeroed every graph replay.
// ---------------------------------------------------------------------------
__global__ __launch_bounds__(256) void prep_q(
    const float* __restrict__ Wgx, const float* __restrict__ Wix,
    const float* __restrict__ Wfx, const float* __restrict__ Wox,
    const float* __restrict__ bg,  const float* __restrict__ bi,
    const float* __restrict__ bf_, const float* __restrict__ bo,
    const float* __restrict__ emb, float* __restrict__ Qp,
    int* __restrict__ ctrl)
{
    int tid = blockIdx.x * blockDim.x + threadIdx.x;   // 0..4095
    if (tid < 512) ctrl[tid] = 0;
    if (tid >= 4096) return;
    int g   = tid >> 10;
    int hr4 = (tid & 1023) >> 2;
    int v   = tid & 3;
    const float* Wx = (g == 0) ? Wgx : (g == 1) ? Wix : (g == 2) ? Wfx : Wox;
    const float* bb = (g == 0) ? bg  : (g == 1) ? bi  : (g == 2) ? bf_ : bo;
    f32x4 o;
#pragma unroll
    for (int reg = 0; reg < 4; ++reg) {
        int row = hr4 * 4 + reg;
        float s = bb[row];
        if (v < kV) {
#pragma unroll
            for (int e = 0; e < kE; ++e) s += Wx[row * kE + e] * emb[v * kE + e];
        }
        o[reg] = s;
    }
    *(f32x4*)(Qp + (size_t)tid * 4) = o;
}

// one K-half: 16 k0 steps, 8-slot ring with lookahead 6
#define K_HALF(KB, HR0, HR1)                                                 \
  {                                                                          \
    s16x8 br[8][2];                                                          \
    _Pragma("unroll")                                                        \
    for (int s = 0; s < 6; ++s) {                                            \
      br[s][0] = *(const s16x8*)((HR0) + s * 32);                            \
      br[s][1] = *(const s16x8*)((HR1) + s * 32);                            \
    }                                                                        \
    _Pragma("unroll")                                                        \
    for (int i = 0; i < 16; ++i) {                                           \
      if (i + 6 < 16) {                                                      \
        const int s = (i + 6) & 7;                                           \
        br[s][0] = *(const s16x8*)((HR0) + (i + 6) * 32);                    \
        br[s][1] = *(const s16x8*)((HR1) + (i + 6) * 32);                    \
      }                                                                      \
      const int cur = i & 7;                                                 \
      const int cbo = (((KB) >> 3) + (i >> 3)) * 16384;                      \
      _Pragma("unroll")                                                      \
      for (int g = 0; g < 4; ++g) {                                          \
        const int fo = cbo + ((g * 8 + (i & 7)) * 64 + lane) * 8;            \
        s16x8 a = *(const s16x8*)&wlds[fo];                                  \
        acc[g][0] = __builtin_amdgcn_mfma_f32_16x16x32_bf16(a, br[cur][0],   \
                                                            acc[g][0], 0, 0, 0); \
        acc[g][1] = __builtin_amdgcn_mfma_f32_16x16x32_bf16(a, br[cur][1],   \
                                                            acc[g][1], 0, 0, 0); \
      }                                                                      \
    }                                                                        \
  }

// ---------------------------------------------------------------------------
// Persistent LSTM: 256 blocks x 512 thr (1 block/CU, 8 waves), weights
// LDS-resident, K-split overlap exchange.
// Identity: xcc = XCC_ID, rank = arrival order in XCD (0..31).
// p = xcc>>1, side = xcc&1, q = side*32+rank, partner qprt = (1-side)*32+rank.
// hbuf (hA/hB): [q 64][col 1024][16] shorts. xcdbuf: per (xcc,parity),
// [col 256][k 1024] shorts.
// ---------------------------------------------------------------------------
__global__ __launch_bounds__(512, 2) void lstm_persist(
    const u16* __restrict__ wsw, const float* __restrict__ Qp,
    const int* __restrict__ x,
    u16* __restrict__ hA, u16* __restrict__ hB,
    const float* __restrict__ cT, int* __restrict__ ctrl,
    u16* __restrict__ xcb)
{
    __shared__ u16 wlds[65536];   // 128 KB, resident all 127 steps
    __shared__ int sh_ids[2];

    const int tid  = threadIdx.x;
    const int lane = tid & 63;
    const int wave = tid >> 6;              // 0..7
    const int lm   = lane & 15;
    const int quad = lane >> 4;

    // ---- runtime identity: XCD id + arrival rank within XCD ----
    if (tid == 0) {
        unsigned xccr;
        asm volatile("s_getreg_b32 %0, hwreg(HW_REG_XCC_ID)" : "=s"(xccr));
        int rank = atomicAdd(ctrl + 288 + (xccr & 7), 1);
        sh_ids[0] = (int)(xccr & 7);
        sh_ids[1] = rank;
    }
    __syncthreads();
    const int xcc   = sh_ids[0];
    const int rank  = sh_ids[1];              // 0..31 within XCD
    const int p     = xcc >> 1;               // col-group 0..3 (XCD pair)
    const int side  = xcc & 1;
    const int q     = side * 32 + rank;       // row-group 0..63 within pair
    const int qprt  = (1 - side) * 32 + rank; // partner row-group
    const int r0  = q * 16;
    const int cl0 = wave * 32;                // wave's local col base (0..255)
    const int c0  = p * 256 + cl0;            // global col base

    int* pflag = ctrl;              // [p*64 + q], monotonic step counters
    int* lcnt  = ctrl + 256;        // [xcc], local-epilogue rounds
    int* rcnt  = ctrl + 272;        // [xcc], remote-fetch rounds

    const u16* wswblk = wsw + (size_t)q * 65536;

    // ---- stage the whole weight slice once (async, 128 KB) ----
#pragma unroll
    for (int rr = 0; rr < 16; ++rr) {
        const int ub = wave * 8192 + rr * 512;   // shorts
        async_copy16(wswblk + ub + lane * 8, &wlds[ub]);
    }

    // ---- persistent c state: loaded once, lives in registers 127 steps ----
    f32x4 creg[2];
#pragma unroll
    for (int nt = 0; nt < 2; ++nt)
        creg[nt] = *(const f32x4*)(cT +
            (size_t)(c0 + nt * 16 + lm) * kH + r0 + quad * 4);

    const int* xp0 = x + (size_t)(c0 + lm) * kS;
    const int* xp1 = x + (size_t)(c0 + 16 + lm) * kS;
    const int koff = quad * 8;
    const int lkb = side * 16;          // local K half base (k0 units)
    const int rkb = (1 - side) * 16;    // remote K half base

    asm volatile("s_waitcnt vmcnt(0)" ::: "memory");
    __syncthreads();   // weights resident from here on

#pragma unroll 1
    for (int t = 0; t < kT; ++t) {
        u16* xbase = xcb + (size_t)(xcc * 2 + (t & 1)) * 262144;        // h_t
        u16* xw    = xcb + (size_t)(xcc * 2 + ((t + 1) & 1)) * 262144;  // h_{t+1}
        const u16* hsrc = (t & 1) ? hB : hA;   // global h_t   (fetch source)
        u16*       hdst = (t & 1) ? hA : hB;   // global h_{t+1}

        // ---- gate A: local half of h_t staged by local epilogues ----
        // (sc0 sc1 poll: counters live at the coherent point, NOT in L2)
        if (t >= 1) {
            if (tid == 0) {
                const int* cp = lcnt + xcc;
                const int tgt = 32 * t;
                for (;;) {
                    int v;
                    asm volatile("global_load_dword %0, %1, off sc0 sc1\n\t"
                                 "s_waitcnt vmcnt(0)"
                                 : "=v"(v) : "v"(cp) : "memory");
                    if (v >= tgt) break;
                    __builtin_amdgcn_s_sleep(1);
                }
            }
            __syncthreads();
            asm volatile("buffer_inv" ::: "memory");   // vL1 only
        }

        // ---- per-step loads: x -> vv -> Qp vectors (L1/L2-warm) ----
        int vv[2];
        {
            int v0 = xp0[t]; vv[0] = (v0 < 0) ? 0 : (v0 > kV - 1) ? (kV - 1) : v0;
            int v1 = xp1[t]; vv[1] = (v1 < 0) ? 0 : (v1 > kV - 1) ? (kV - 1) : v1;
        }
        f32x4 qv[2][4];
#pragma unroll
        for (int nt = 0; nt < 2; ++nt)
#pragma unroll
            for (int g = 0; g < 4; ++g)
                qv[nt][g] = *(const f32x4*)(Qp +
                    (size_t)(((g * 256 + q * 4 + quad) * 4 + vv[nt]) * 4));

        f32x4 acc[4][2];
        const f32x4 zero = {0.f, 0.f, 0.f, 0.f};
#pragma unroll
        for (int g = 0; g < 4; ++g)
#pragma unroll
            for (int n = 0; n < 2; ++n) acc[g][n] = zero;

        // ---- LOCAL K half (rows produced on this XCD; warm local L2) ----
        {
            const u16* hr0 = xbase + (size_t)(cl0 + lm) * kH + lkb * 32 + koff;
            const u16* hr1 = xbase + (size_t)(cl0 + 16 + lm) * kH + lkb * 32 + koff;
            K_HALF(lkb, hr0, hr1)
        }

        // ---- mid-step: stage the remote half (partner chunk, dedup'd) ----
        if (t >= 1) {
            if (tid == 0) {
                const int* pp = pflag + p * 64 + qprt;
                for (;;) {
                    int v;
                    asm volatile("global_load_dword %0, %1, off sc0 sc1\n\t"
                                 "s_waitcnt vmcnt(0)"
                                 : "=v"(v) : "v"(pp) : "memory");
                    if (v >= t) break;
                    __builtin_amdgcn_s_sleep(1);
                }
            }
            __syncthreads();
            {   // fetch 16 B/thread: partner's contiguous 8 KB chunk
                const int cl = tid >> 1;
                const int hf = tid & 1;
                const u16* srcp = hsrc +
                    ((size_t)qprt * 1024 + p * 256 + cl) * 16 + hf * 8;
                u16* dstp = xbase + (size_t)cl * kH + qprt * 16 + hf * 8;
                i32x4 v;
                asm volatile("global_load_dwordx4 %0, %1, off sc0 sc1\n\t"
                             "s_waitcnt vmcnt(0)"
                             : "=&v"(v) : "v"(srcp) : "memory");
                *(i32x4*)dstp = v;
            }
            asm volatile("s_waitcnt vmcnt(0)" ::: "memory");
            __syncthreads();
            if (tid == 0) {
                atomicAdd(rcnt + xcc, 1);
                const int* cp = rcnt + xcc;
                const int tgt = 32 * t;
                for (;;) {
                    int v;
                    asm volatile("global_load_dword %0, %1, off sc0 sc1\n\t"
                                 "s_waitcnt vmcnt(0)"
                                 : "=v"(v) : "v"(cp) : "memory");
                    if (v >= tgt) break;
                    __builtin_amdgcn_s_sleep(1);
                }
            }
            __syncthreads();
            asm volatile("buffer_inv" ::: "memory");   // vL1 only
        }

        // ---- REMOTE K half ----
        {
            const u16* hr0 = xbase + (size_t)(cl0 + lm) * kH + rkb * 32 + koff;
            const u16* hr1 = xbase + (size_t)(cl0 + 16 + lm) * kH + rkb * 32 + koff;
            K_HALF(rkb, hr0, hr1)
        }

        // ---- epilogue: ALU + dual store. C/D: col=lane&15, row=quad*4+reg
#pragma unroll
        for (int nt = 0; nt < 2; ++nt) {
            const int cl = cl0 + nt * 16 + lm;         // local col 0..255
            const int c  = p * 256 + cl;               // global col
            const int rb = r0 + quad * 4;
            f32x4 cnew;
            s16x4 hnew;
#pragma unroll
            for (int reg = 0; reg < 4; ++reg) {
                float pg = clamp30(acc[0][nt][reg] + qv[nt][0][reg]);
                float pi = clamp30(acc[1][nt][reg] + qv[nt][1][reg]);
                float pf = clamp30(acc[2][nt][reg] + qv[nt][2][reg]);
                float po = clamp30(acc[3][nt][reg] + qv[nt][3][reg]);
                float gg = tanh_fast(pg);
                float ii = sigmoid_fast(pi);
                float ff = sigmoid_fast(pf);
                float oo = sigmoid_fast(po);
                float c2 = gg * ii + creg[nt][reg] * ff;
                c2 = fminf(fmaxf(c2, -200.0f), 200.0f);
                cnew[reg] = c2;
                hnew[reg] = (short)f2b(tanh_fast(c2) * oo);
            }
            creg[nt] = cnew;
            i32x2 hv;
            __builtin_memcpy(&hv, &hnew, 8);
            // cross-XCD medium (partner fetch + logits): [q][c][16] layout
            short* hp = (short*)hdst + ((size_t)q * 1024 + c) * 16 + quad * 4;
            asm volatile("global_store_dwordx2 %0, %1, off sc0 sc1"
                         :: "v"(hp), "v"(hv) : "memory");
            // local copy through this XCD's L2 (consumed by local K-loops)
            *(s16x4*)(xw + (size_t)cl * kH + rb) = hnew;
        }

        if (t < kT - 1) {
            asm volatile("s_waitcnt vmcnt(0)" ::: "memory");  // stores done
            __syncthreads();                                  // block done
            if (tid == 0) {
                int* fp = pflag + p * 64 + q;
                int fv = t + 1;
                asm volatile("global_store_dword %0, %1, off sc0 sc1\n\t"
                             "s_waitcnt vmcnt(0)"
                             :: "v"(fp), "v"(fv) : "memory");
                atomicAdd(lcnt + xcc, 1);
            }
        }
    }
}

// ---------------------------------------------------------------------------
// Logits: p[b][cls] = h[b,:] . W_ph[cls,:] + b_p[cls]; log_softmax over 10.
// h buffer layout: [q 64][col 1024][16] shorts.
// ---------------------------------------------------------------------------
__global__ __launch_bounds__(256) void logits_kernel(
    const u16* __restrict__ hT, const float* __restrict__ Wph,
    const float* __restrict__ bp, float* __restrict__ out)
{
    const int wave = threadIdx.x >> 6;
    const int lane = threadIdx.x & 63;
    const int b = blockIdx.x * 4 + wave;

    const u16* hp = hT + ((size_t)lane * 1024 + b) * 16;   // q = lane
    float hf[16];
#pragma unroll
    for (int j = 0; j < 16; ++j) hf[j] = b2f(hp[j]);

    float p[kC];
#pragma unroll
    for (int cls = 0; cls < kC; ++cls) {
        const float* wp = Wph + (size_t)cls * kH + lane * 16;
        float s = 0.f;
#pragma unroll
        for (int j = 0; j < 16; ++j) s += hf[j] * wp[j];
#pragma unroll
        for (int off = 1; off < 64; off <<= 1) s += __shfl_xor(s, off, 64);
        p[cls] = fminf(fmaxf(s + bp[cls], -1.0e4f), 1.0e4f);
    }

    float m = p[0];
#pragma unroll
    for (int cls = 1; cls < kC; ++cls) m = fmaxf(m, p[cls]);
    float se = 0.f;
#pragma unroll
    for (int cls = 0; cls < kC; ++cls) se += __expf(p[cls] - m);
    float l = m + __logf(se);

    if (lane < kC) {
        float myp = p[0];
#pragma unroll
        for (int cls = 1; cls < kC; ++cls)
            if (lane == cls) myp = p[cls];
        out[(size_t)b * kC + lane] = myp - l;
    }
}

// ---------------------------------------------------------------------------
extern "C" void kernel_launch(void* const* d_in, const int* in_sizes, int n_in,
                              void* d_out, int out_size, void* d_ws, size_t ws_size,
                              hipStream_t stream)
{
    const int*   x   = (const int*)  d_in[0];
    const float* emb = (const float*)d_in[1];
    const float* Wgx = (const float*)d_in[2];
    const float* Wgh = (const float*)d_in[3];
    const float* bg  = (const float*)d_in[4];
    const float* Wix = (const float*)d_in[5];
    const float* Wih = (const float*)d_in[6];
    const float* bi  = (const float*)d_in[7];
    const float* Wfx = (const float*)d_in[8];
    const float* Wfh = (const float*)d_in[9];
    const float* bf_ = (const float*)d_in[10];
    const float* Wox = (const float*)d_in[11];
    const float* Woh = (const float*)d_in[12];
    const float* bo  = (const float*)d_in[13];
    const float* Wph = (const float*)d_in[14];
    const float* bp  = (const float*)d_in[15];
    const float* h0  = (const float*)d_in[16];
    const float* c0  = (const float*)d_in[17];

    char* ws = (char*)d_ws;
    float* Qp  = (float*)ws;                              // 64 KB
    u16*   hA  = (u16*)(ws + (64 << 10));                 // 2 MB  [64][1024][16]
    u16*   hB  = hA + (size_t)kB * kH;                    // 2 MB
    float* cT  = (float*)(hB + (size_t)kB * kH);          // 4 MB
    u16*   wsw = (u16*)(cT + (size_t)kB * kH);            // 8 MB
    u16*   xcb = wsw + (size_t)64 * 65536;                // 8 MB (16 x 512 KB)
    int*   ctrl = (int*)(xcb + (size_t)16 * 262144);      // 2 KB (total ~24.1 MB)

    prep_weights<<<dim3(2048), dim3(256), 0, stream>>>(Wgh, Wih, Wfh, Woh, wsw);
    prep_hc<<<dim3(kB / 32, kH / 32), dim3(32, 32), 0, stream>>>(h0, c0, xcb, cT);
    prep_q<<<dim3(16), dim3(256), 0, stream>>>(Wgx, Wix, Wfx, Wox, bg, bi, bf_, bo,
                                               emb, Qp, ctrl);

    lstm_persist<<<dim3(256), dim3(512), 0, stream>>>(
        wsw, Qp, x, hA, hB, cT, ctrl, xcb);

    // 127 steps: t=126 (even) wrote hB.
    logits_kernel<<<dim3(kB / 4), dim3(256), 0, stream>>>(hB, Wph, bp, (float*)d_out);
}

// Round 7
// 2760.015 us; speedup vs baseline: 1.1137x; 1.0893x over previous
//
#include <hip/hip_runtime.h>

// LSTM: H=1024, B=1024, S=128 (T=127 steps), E=6, V=3, C=10.
// R19 = R14 (persistent, LDS-resident weights, simple 256-flag barrier +
// per-block acquire fence -- fastest CLEAN variant, no outliers) with ONE
// change: all data loads in lstm_persist (b-ring h reads, x, Qp, cT) are
// forced to address_space(1) global_load.
// Theory: generic-pointer loads can emit flat_load, which increments BOTH
// vmcnt and lgkmcnt; every compiler lgkmcnt wait guarding ds_read->MFMA then
// also waits for in-flight b-loads (~200-900 cyc), serializing the K-loop on
// memory latency. Evidence: R18's warm-L2 b-source didn't speed the K-loop
// at all, and R12 (multi-launch, cold) == R14 (persistent, warm) per-step.
// Explicit AS1 loads are vmcnt-only -> ds_read waits decouple from b-loads.
constexpr int kH = 1024;
constexpr int kB = 1024;
constexpr int kS = 128;
constexpr int kT = 127;
constexpr int kE = 6;
constexpr int kV = 3;
constexpr int kC = 10;

typedef short s16x8 __attribute__((ext_vector_type(8)));
typedef short s16x4 __attribute__((ext_vector_type(4)));
typedef float f32x4 __attribute__((ext_vector_type(4)));
typedef int   i32x2 __attribute__((ext_vector_type(2)));
typedef int   i32x4 __attribute__((ext_vector_type(4)));
typedef unsigned short u16;

// explicit global-address-space load pointers (vmcnt-only global_load)
typedef const __attribute__((address_space(1))) s16x8* gas_s16x8;
typedef const __attribute__((address_space(1))) f32x4* gas_f32x4;
typedef const __attribute__((address_space(1))) int*   gas_int;

__device__ __forceinline__ float b2f(u16 u) {
    return __uint_as_float(((unsigned)u) << 16);
}
__device__ __forceinline__ u16 f2b(float f) {
    unsigned u = __float_as_uint(f);
    return (u16)((u + 0x7FFFu + ((u >> 16) & 1u)) >> 16);   // RNE
}
__device__ __forceinline__ float sigmoid_fast(float x) {
    return 1.0f / (1.0f + __expf(-x));
}
__device__ __forceinline__ float tanh_fast(float x) {
    return 2.0f / (1.0f + __expf(-2.0f * x)) - 1.0f;
}
__device__ __forceinline__ float clamp30(float x) {
    return fminf(fmaxf(x, -30.0f), 30.0f);
}

__device__ __forceinline__ void async_copy16(const u16* g, u16* l) {
    __builtin_amdgcn_global_load_lds(
        (const __attribute__((address_space(1))) void*)g,
        (__attribute__((address_space(3))) void*)l, 16, 0, 0);
}

// ---------------------------------------------------------------------------
// Prep 1: weights fp32 -> bf16, frag-major (identical to R8..R18):
//   grp = (((by*4 + kc)*4 + g)*8 + k0)*64 + lane
//   wsw[grp*8 + j] = W_g[by*16 + (lane&15)][kc*256 + k0*32 + (lane>>4)*8 + j]
// ---------------------------------------------------------------------------
__global__ __launch_bounds__(256) void prep_weights(
    const float* __restrict__ Wgh, const float* __restrict__ Wih,
    const float* __restrict__ Wfh, const float* __restrict__ Woh,
    u16* __restrict__ wsw)
{
    unsigned grp = blockIdx.x * 256 + threadIdx.x;    // 0 .. 2^19-1
    const int lane = grp & 63;
    const int lm   = lane & 15;
    const int quad = lane >> 4;
    const int k0   = (grp >> 6) & 7;
    const int g    = (grp >> 9) & 3;
    const int kc   = (grp >> 11) & 3;
    const int by   = grp >> 13;                       // 0..63
    const float* src = (g == 0) ? Wgh : (g == 1) ? Wih : (g == 2) ? Wfh : Woh;
    const int row = by * 16 + lm;
    const int k   = kc * 256 + k0 * 32 + quad * 8;
    f32x4 v0 = *(const f32x4*)(src + (size_t)row * kH + k);
    f32x4 v1 = *(const f32x4*)(src + (size_t)row * kH + k + 4);
    s16x8 o;
#pragma unroll
    for (int j = 0; j < 4; ++j) o[j] = (short)f2b(v0[j]);
#pragma unroll
    for (int j = 0; j < 4; ++j) o[4 + j] = (short)f2b(v1[j]);
    *(s16x8*)(wsw + (size_t)grp * 8) = o;
}

// ---------------------------------------------------------------------------
// Prep 2: transpose h0 (H,B) fp32 -> hA (B,H) bf16; c0 (H,B) -> cT (B,H) fp32.
// ---------------------------------------------------------------------------
__global__ __launch_bounds__(1024) void prep_hc(
    const float* __restrict__ h0, const float* __restrict__ c0,
    u16* __restrict__ hA, float* __restrict__ cT)
{
    __shared__ float th[32][33];
    __shared__ float tc[32][33];
    int b = blockIdx.x * 32 + threadIdx.x;
    int h = blockIdx.y * 32 + threadIdx.y;
    th[threadIdx.y][threadIdx.x] = h0[(size_t)h * kB + b];
    tc[threadIdx.y][threadIdx.x] = c0[(size_t)h * kB + b];
    __syncthreads();
    int ob = blockIdx.x * 32 + threadIdx.y;
    int oh = blockIdx.y * 32 + threadIdx.x;
    hA[(size_t)ob * kH + oh] = f2b(th[threadIdx.x][threadIdx.y]);
    cT[(size_t)ob * kH + oh] = tc[threadIdx.x][threadIdx.y];
}

// ---------------------------------------------------------------------------
// Prep 3: gate constants repacked as f32x4 (unchanged), plus zeroing the
// barrier flags (re-zeroed every graph replay, stream-ordered before the
// persistent kernel).
// ---------------------------------------------------------------------------
__global__ __launch_bounds__(256) void prep_q(
    const float* __restrict__ Wgx, const float* __restrict__ Wix,
    const float* __restrict__ Wfx, const float* __restrict__ Wox,
    const float* __restrict__ bg,  const float* __restrict__ bi,
    const float* __restrict__ bf_, const float* __restrict__ bo,
    const float* __restrict__ emb, float* __restrict__ Qp,
    int* __restrict__ flags)
{
    int tid = blockIdx.x * blockDim.x + threadIdx.x;   // 0..4095
    if (tid < 512) flags[tid] = 0;
    if (tid >= 4096) return;
    int g   = tid >> 10;
    int hr4 = (tid & 1023) >> 2;
    int v   = tid & 3;
    const float* Wx = (g == 0) ? Wgx : (g == 1) ? Wix : (g == 2) ? Wfx : Wox;
    const float* bb = (g == 0) ? bg  : (g == 1) ? bi  : (g == 2) ? bf_ : bo;
    f32x4 o;
#pragma unroll
    for (int reg = 0; reg < 4; ++reg) {
        int row = hr4 * 4 + reg;
        float s = bb[row];
        if (v < kV) {
#pragma unroll
            for (int e = 0; e < kE; ++e) s += Wx[row * kE + e] * emb[v * kE + e];
        }
        o[reg] = s;
    }
    *(f32x4*)(Qp + (size_t)tid * 4) = o;
}

// ---------------------------------------------------------------------------
// Persistent LSTM, LDS-resident weights: all 127 timesteps in one launch.
// Grid 256 x 512 thr (1 block/CU, 8 waves). Block tile: 16 h-rows x 4 gates
// x 256 cols; wave w: cols [bx*256 + 32w, +32) (nt=2).
// XCD swizzle: xcd=blk&7, slot=blk>>3 (0..31), by=xcd*8+(slot&7) (0..63),
// bx=slot>>3 (0..3).
// Weights: full 128 KB by-slice staged to LDS once at t=0; K-loop has no
// global staging and no barriers. All data loads are explicit AS1 global.
// ---------------------------------------------------------------------------
__global__ __launch_bounds__(512, 2) void lstm_persist(
    const u16* __restrict__ wsw, const float* __restrict__ Qp,
    const int* __restrict__ x,
    short* __restrict__ hA, short* __restrict__ hB,
    const float* __restrict__ cT, int* __restrict__ flags)
{
    __shared__ u16 wlds[65536];   // 128 KB, resident all 127 steps

    const int tid  = threadIdx.x;
    const int lane = tid & 63;
    const int wave = tid >> 6;              // 0..7
    const int lm   = lane & 15;
    const int quad = lane >> 4;
    const int blk  = blockIdx.x;            // 0..255
    const int xcd  = blk & 7;
    const int slot = blk >> 3;              // 0..31
    const int by   = xcd * 8 + (slot & 7);  // 0..63
    const int bx   = slot >> 3;             // 0..3
    const int r0 = by * 16;
    const int c0 = bx * 256 + wave * 32;

    const u16* wswblk = wsw + (size_t)by * 65536;

    // ---- stage the whole weight slice once (async, 128 KB) ----
#pragma unroll
    for (int rr = 0; rr < 16; ++rr) {
        const int ub = wave * 8192 + rr * 512;   // shorts
        async_copy16(wswblk + ub + lane * 8, &wlds[ub]);
    }

    // ---- persistent c state: loaded once, lives in registers 127 steps ----
    f32x4 creg[2];
#pragma unroll
    for (int nt = 0; nt < 2; ++nt)
        creg[nt] = *(gas_f32x4)(cT +
            (size_t)(c0 + nt * 16 + lm) * kH + r0 + quad * 4);

    const int* xp0 = x + (size_t)(c0 + lm) * kS;
    const int* xp1 = x + (size_t)(c0 + 16 + lm) * kS;
    const int koff = quad * 8;

    asm volatile("s_waitcnt vmcnt(0)" ::: "memory");
    __syncthreads();   // weights resident from here on

#pragma unroll 1
    for (int t = 0; t < kT; ++t) {
        const short* hin  = (t & 1) ? hB : hA;
        short*       hout = (t & 1) ? hA : hB;

        // ---- per-step loads: x -> vv -> Qp vectors (AS1 loads) ----
        int vv[2];
        {
            int v0 = *(gas_int)(xp0 + t);
            vv[0] = (v0 < 0) ? 0 : (v0 > kV - 1) ? (kV - 1) : v0;
            int v1 = *(gas_int)(xp1 + t);
            vv[1] = (v1 < 0) ? 0 : (v1 > kV - 1) ? (kV - 1) : v1;
        }
        f32x4 qv[2][4];
#pragma unroll
        for (int nt = 0; nt < 2; ++nt)
#pragma unroll
            for (int g = 0; g < 4; ++g)
                qv[nt][g] = *(gas_f32x4)(Qp +
                    (size_t)(((g * 256 + by * 4 + quad) * 4 + vv[nt]) * 4));

        // ---- b-ring prologue: slots 0..4 (6-slot ring, lookahead 5) ----
        const short* hrow0 = hin + (size_t)(c0 + lm) * kH + koff;
        const short* hrow1 = hin + (size_t)(c0 + 16 + lm) * kH + koff;
        s16x8 br[6][2];
#pragma unroll
        for (int s = 0; s < 5; ++s) {
            br[s][0] = *(gas_s16x8)(hrow0 + s * 32);
            br[s][1] = *(gas_s16x8)(hrow1 + s * 32);
        }

        f32x4 acc[4][2];
        const f32x4 zero = {0.f, 0.f, 0.f, 0.f};
#pragma unroll
        for (int g = 0; g < 4; ++g)
#pragma unroll
            for (int n = 0; n < 2; ++n) acc[g][n] = zero;

        // ---- main K loop: 32 x (4 ds_read_b128 + 8 MFMA), ring loads ----
#pragma unroll
        for (int k0 = 0; k0 < 32; ++k0) {
            if (k0 + 5 < 32) {
                const int s = (k0 + 5) % 6;
                br[s][0] = *(gas_s16x8)(hrow0 + (k0 + 5) * 32);
                br[s][1] = *(gas_s16x8)(hrow1 + (k0 + 5) * 32);
            }
            const int cur = k0 % 6;
            const int cb = (k0 >> 3) * 16384;         // K-chunk base (shorts)
#pragma unroll
            for (int g = 0; g < 4; ++g) {
                const int f = cb + ((g * 8 + (k0 & 7)) * 64 + lane) * 8;
                s16x8 a = *(const s16x8*)&wlds[f];
                acc[g][0] = __builtin_amdgcn_mfma_f32_16x16x32_bf16(a, br[cur][0], acc[g][0], 0, 0, 0);
                acc[g][1] = __builtin_amdgcn_mfma_f32_16x16x32_bf16(a, br[cur][1], acc[g][1], 0, 0, 0);
            }
        }

        // ---- epilogue: ALU + coherent h store. C/D: col=lane&15, row=quad*4+reg
#pragma unroll
        for (int nt = 0; nt < 2; ++nt) {
            const int c = c0 + nt * 16 + lm;
            const int rb = r0 + quad * 4;
            f32x4 cnew;
            s16x4 hnew;
#pragma unroll
            for (int reg = 0; reg < 4; ++reg) {
                float pg = clamp30(acc[0][nt][reg] + qv[nt][0][reg]);
                float pi = clamp30(acc[1][nt][reg] + qv[nt][1][reg]);
                float pf = clamp30(acc[2][nt][reg] + qv[nt][2][reg]);
                float po = clamp30(acc[3][nt][reg] + qv[nt][3][reg]);
                float gg = tanh_fast(pg);
                float ii = sigmoid_fast(pi);
                float ff = sigmoid_fast(pf);
                float oo = sigmoid_fast(po);
                float c2 = gg * ii + creg[nt][reg] * ff;
                c2 = fminf(fmaxf(c2, -200.0f), 200.0f);
                cnew[reg] = c2;
                hnew[reg] = (short)f2b(tanh_fast(c2) * oo);
            }
            creg[nt] = cnew;
            i32x2 hv;
            __builtin_memcpy(&hv, &hnew, 8);
            short* hp = hout + (size_t)c * kH + rb;
            // write-through to L3: device-visible once vmcnt drains.
            asm volatile("global_store_dwordx2 %0, %1, off sc0 sc1"
                         :: "v"(hp), "v"(hv) : "memory");
        }

        if (t < kT - 1) {
            // ---- grid barrier across 256 blocks ----
            asm volatile("s_waitcnt vmcnt(0)" ::: "memory");  // own h stores done
            __syncthreads();                                  // whole block done
            if (tid < 64) {
                if (tid == 0) {
                    int* fp = flags + blk;
                    int fv = t + 1;
                    asm volatile("global_store_dword %0, %1, off sc0 sc1\n\t"
                                 "s_waitcnt vmcnt(0)"
                                 :: "v"(fp), "v"(fv) : "memory");
                }
                const int* fp = flags + lane * 4;   // 64 lanes x 4 = all 256
                for (;;) {
                    i32x4 fa;
                    asm volatile(
                        "global_load_dwordx4 %0, %1, off sc0 sc1\n\t"
                        "s_waitcnt vmcnt(0)"
                        : "=&v"(fa) : "v"(fp) : "memory");
                    int ok = (fa.x > t) & (fa.y > t) & (fa.z > t) & (fa.w > t);
                    if (__all(ok)) break;
                    __builtin_amdgcn_s_sleep(1);
                }
                // ONE acquire per block per step: invalidates this CU's L1 +
                // this XCD's L2 so next step's cached h reads are fresh.
                // Weights are in LDS -> immune to the invalidate.
                __builtin_amdgcn_fence(__ATOMIC_ACQUIRE, "agent");
            }
            __syncthreads();
        }
    }
}

// ---------------------------------------------------------------------------
// Logits: p[b][cls] = h[b,:] . W_ph[cls,:] + b_p[cls]; log_softmax over 10.
// ---------------------------------------------------------------------------
__global__ __launch_bounds__(256) void logits_kernel(
    const u16* __restrict__ hT, const float* __restrict__ Wph,
    const float* __restrict__ bp, float* __restrict__ out)
{
    const int wave = threadIdx.x >> 6;
    const int lane = threadIdx.x & 63;
    const int b = blockIdx.x * 4 + wave;

    const u16* hp = hT + (size_t)b * kH + lane * 16;
    float hf[16];
#pragma unroll
    for (int j = 0; j < 16; ++j) hf[j] = b2f(hp[j]);

    float p[kC];
#pragma unroll
    for (int cls = 0; cls < kC; ++cls) {
        const float* wp = Wph + (size_t)cls * kH + lane * 16;
        float s = 0.f;
#pragma unroll
        for (int j = 0; j < 16; ++j) s += hf[j] * wp[j];
#pragma unroll
        for (int off = 1; off < 64; off <<= 1) s += __shfl_xor(s, off, 64);
        p[cls] = fminf(fmaxf(s + bp[cls], -1.0e4f), 1.0e4f);
    }

    float m = p[0];
#pragma unroll
    for (int cls = 1; cls < kC; ++cls) m = fmaxf(m, p[cls]);
    float se = 0.f;
#pragma unroll
    for (int cls = 0; cls < kC; ++cls) se += __expf(p[cls] - m);
    float l = m + __logf(se);

    if (lane < kC) {
        float myp = p[0];
#pragma unroll
        for (int cls = 1; cls < kC; ++cls)
            if (lane == cls) myp = p[cls];
        out[(size_t)b * kC + lane] = myp - l;
    }
}

// ---------------------------------------------------------------------------
extern "C" void kernel_launch(void* const* d_in, const int* in_sizes, int n_in,
                              void* d_out, int out_size, void* d_ws, size_t ws_size,
                              hipStream_t stream)
{
    const int*   x   = (const int*)  d_in[0];
    const float* emb = (const float*)d_in[1];
    const float* Wgx = (const float*)d_in[2];
    const float* Wgh = (const float*)d_in[3];
    const float* bg  = (const float*)d_in[4];
    const float* Wix = (const float*)d_in[5];
    const float* Wih = (const float*)d_in[6];
    const float* bi  = (const float*)d_in[7];
    const float* Wfx = (const float*)d_in[8];
    const float* Wfh = (const float*)d_in[9];
    const float* bf_ = (const float*)d_in[10];
    const float* Wox = (const float*)d_in[11];
    const float* Woh = (const float*)d_in[12];
    const float* bo  = (const float*)d_in[13];
    const float* Wph = (const float*)d_in[14];
    const float* bp  = (const float*)d_in[15];
    const float* h0  = (const float*)d_in[16];
    const float* c0  = (const float*)d_in[17];

    char* ws = (char*)d_ws;
    float* Qp  = (float*)ws;                              // 64 KB
    u16*   hA  = (u16*)(ws + (64 << 10));                 // 2 MB
    u16*   hB  = hA + (size_t)kB * kH;                    // 2 MB
    float* cT  = (float*)(hB + (size_t)kB * kH);          // 4 MB
    u16*   wsw = (u16*)(cT + (size_t)kB * kH);            // 8 MB
    int*   flags = (int*)(wsw + (size_t)64 * 65536);      // 2 KB (total ~16.07 MB)

    prep_weights<<<dim3(2048), dim3(256), 0, stream>>>(Wgh, Wih, Wfh, Woh, wsw);
    prep_hc<<<dim3(kB / 32, kH / 32), dim3(32, 32), 0, stream>>>(h0, c0, hA, cT);
    prep_q<<<dim3(16), dim3(256), 0, stream>>>(Wgx, Wix, Wfx, Wox, bg, bi, bf_, bo,
                                               emb, Qp, flags);

    lstm_persist<<<dim3(256), dim3(512), 0, stream>>>(
        wsw, Qp, x, (short*)hA, (short*)hB, cT, flags);

    // 127 steps: t=126 (even) wrote hB.
    logits_kernel<<<dim3(kB / 4), dim3(256), 0, stream>>>(hB, Wph, bp, (float*)d_out);
}